// Round 10
// baseline (270.094 us; speedup 1.0000x reference)
//
#include <hip/hip_runtime.h>

// MPNN regression. R10: GEMM K-loop pipelined AITER-style — raw s_barrier +
// explicit s_waitcnt vmcnt(4) (NOT __syncthreads, whose implicit vmcnt(0)
// drained every prefetch; see R9 post-mortem). 3-deep LDS ring, prefetch
// issued 2 kts ahead stays in flight across the barrier. Packed tile format
// P[mt][kt][ch][row][8] for all GEMM operands (R8). fp16 MFMA, f32 acc.

typedef _Float16 half8 __attribute__((ext_vector_type(8)));
typedef float float4v __attribute__((ext_vector_type(4)));

#define ASYNC_COPY16(gptr, lptr)                                              \
    __builtin_amdgcn_global_load_lds(                                         \
        (const __attribute__((address_space(1))) void*)(gptr),                \
        (__attribute__((address_space(3))) void*)(lptr), 16, 0, 0)

// s_waitcnt imm (gfx9 encoding): vmcnt[3:0] | expcnt[6:4]=7 | lgkmcnt[11:8]=15
#define WAITCNT_VM(n) __builtin_amdgcn_s_waitcnt(0xF70 | (n))

// packed addr (halfs) for element (m,k) of a [*,K] matrix, KT = K/64:
//   ((m/64*KT + k/64)*8 + (k%64)/8)*512 + (m%64)*8 + k%8

// ---------------- fp16 MFMA GEMM body, packed inputs, 3-deep pipeline --------
// C = relu(A1@W1 [+ A2@W2] + bias). Block 64x64, 4 waves of 32x32, BK=64.
// Per wave per kt: exactly 4 global_load_lds (2 A-chunks + 2 B-chunks).
__device__ __forceinline__ void gemm_body(int id,
    const _Float16* __restrict__ A1, int KT1,
    const _Float16* __restrict__ A2, int KT2,
    const _Float16* __restrict__ Wt, int KTw, int ktw2,
    const float* __restrict__ bias, _Float16* __restrict__ C,
    int M, int Mtiles, int packC, int do_relu)
{
    __shared__ _Float16 As[3][4096];   // [ring][ch 0..7][row 0..63][8]  24 KB
    __shared__ _Float16 Bs[3][4096];   // 24 KB

    const int tid  = threadIdx.x;
    const int wave = tid >> 6, lane = tid & 63;

    // swizzle: 8 pn-panels of one mt on consecutive ids == cxcd (mod 8)
    const int cxcd = id & 7, j = id >> 3;
    const int mt = cxcd + 8 * (j >> 3);
    if (mt >= Mtiles) return;
    const int pn = j & 7;
    const int bm = mt * 64, bn = pn * 64;

    const int wr = (wave >> 1) * 32, wc = (wave & 1) * 32;
    const int m16 = lane & 15, quad = lane >> 4;

    float4v acc[2][2] = {};
    float bv[2];
    #pragma unroll
    for (int jj = 0; jj < 2; ++jj) bv[jj] = bias[bn + wc + jj * 16 + m16];

    const int nIter = KT1 + (A2 ? KT2 : 0);

    auto issue = [&](int i, int buf) {
        const bool p2 = (i >= KT1);
        const _Float16* Ab = p2
            ? A2 + (size_t)(mt * KT2 + (i - KT1)) * 4096
            : A1 + (size_t)(mt * KT1 + i) * 4096;
        const _Float16* Wb = Wt
            + (size_t)(pn * KTw + (p2 ? ktw2 + (i - KT1) : i)) * 4096;
        #pragma unroll
        for (int t = 0; t < 2; ++t) {
            const int q = t * 4 + wave;   // 1 KB chunk; dest = base + lane*16
            ASYNC_COPY16(Ab + q * 512 + lane * 8, (char*)&As[buf][0] + q * 1024);
            ASYNC_COPY16(Wb + q * 512 + lane * 8, (char*)&Bs[buf][0] + q * 1024);
        }
    };

    issue(0, 0);
    if (1 < nIter) issue(1, 1);

    for (int i = 0; i < nIter; ++i) {
        const int buf = i % 3;
        // Wait only the OLDEST 4 loads (this kt's buffer); the next buffer's
        // 4 loads stay in flight across the barrier (per-wave FIFO retire).
        if (i + 1 < nIter) WAITCNT_VM(4); else WAITCNT_VM(0);
        __builtin_amdgcn_s_barrier();
        asm volatile("" ::: "memory");   // compiler ordering fence (no code)
        if (i + 2 < nIter) issue(i + 2, (i + 2) % 3);  // overwrites buf (i-1): safe
        #pragma unroll
        for (int c = 0; c < 2; ++c) {
            half8 af[2], bf[2];
            #pragma unroll
            for (int i2 = 0; i2 < 2; ++i2)
                af[i2] = *(const half8*)
                    &As[buf][((c * 4 + quad) * 64 + wr + i2 * 16 + m16) * 8];
            #pragma unroll
            for (int j2 = 0; j2 < 2; ++j2)
                bf[j2] = *(const half8*)
                    &Bs[buf][((c * 4 + quad) * 64 + wc + j2 * 16 + m16) * 8];
            #pragma unroll
            for (int i2 = 0; i2 < 2; ++i2)
                #pragma unroll
                for (int j2 = 0; j2 < 2; ++j2)
                    acc[i2][j2] = __builtin_amdgcn_mfma_f32_16x16x32_f16(
                        af[i2], bf[j2], acc[i2][j2], 0, 0, 0);
        }
        asm volatile("" ::: "memory");
    }

    // epilogue: D layout col=lane&15, row=quad*4+reg
    #pragma unroll
    for (int i = 0; i < 2; ++i)
        #pragma unroll
        for (int rg = 0; rg < 4; ++rg) {
            const int r2 = wr + i * 16 + quad * 4 + rg;
            const int row = bm + r2;
            if (row >= M) continue;
            #pragma unroll
            for (int j2 = 0; j2 < 2; ++j2) {
                float v = acc[i][j2][rg] + bv[j2];
                if (do_relu) v = fmaxf(v, 0.f);
                const int coff = wc + j2 * 16 + m16;
                if (packC) {
                    C[(size_t)((mt * 8 + pn) * 8 + (coff >> 3)) * 512
                      + r2 * 8 + (coff & 7)] = (_Float16)v;
                } else {
                    C[(size_t)row * 512 + bn + coff] = (_Float16)v;
                }
            }
        }
}

__global__ __launch_bounds__(256) void gemm_f16(
    const _Float16* __restrict__ A1, int KT1,
    const _Float16* __restrict__ A2, int KT2,
    const _Float16* __restrict__ Wt, int KTw, int ktw2,
    const float* __restrict__ bias, _Float16* __restrict__ C,
    int M, int Mtiles, int packC, int do_relu)
{
    gemm_body(blockIdx.x, A1, KT1, A2, KT2, Wt, KTw, ktw2,
              bias, C, M, Mtiles, packC, do_relu);
}

// ------- fused: CSR fill (independent) || in-GEMM h0 = relu(x@W_in+b) -------
__global__ __launch_bounds__(256) void fill_ingemm(
    const int* __restrict__ eidx, int* __restrict__ cursor,
    int* __restrict__ srcs, int E,
    const _Float16* __restrict__ xb, const _Float16* __restrict__ WinT,
    const float* __restrict__ b_in, _Float16* __restrict__ B0,
    int M, int Mtiles)
{
    const int fillU = (E + 255) >> 8;
    if ((int)blockIdx.x < fillU) {
        const int e = blockIdx.x * 256 + threadIdx.x;
        if (e < E) {
            const int pos = atomicAdd(&cursor[eidx[E + e]], 1);
            srcs[pos] = eidx[e];
        }
        return;
    }
    gemm_body(blockIdx.x - fillU, xb, 4, nullptr, 0, WinT, 4, 0,
              b_in, B0, M, Mtiles, 1, 1);
}

// ------- prep: weight transpose->packed + x cast->packed + count_deg -------
// (deg is zeroed by a prior hipMemsetAsync on the same stream)
__global__ __launch_bounds__(256) void prep(
    const float* __restrict__ W_in,  _Float16* __restrict__ WinT,
    const float* __restrict__ msg_W, _Float16* __restrict__ msgT,
    const float* __restrict__ upd_W, _Float16* __restrict__ updT,
    const float* __restrict__ x,     _Float16* __restrict__ xb,
    const int* __restrict__ eidx, int* __restrict__ deg, int E,
    int n4, int M)
{
    const int b = blockIdx.x;
    const int tid = threadIdx.x;
    const int castU = (n4 + 255) >> 8;
    if (b < 1664) {
        const float* src; _Float16* dst; int R; int tb;
        if (b < 128)       { src = W_in;               dst = WinT;              R = 256;  tb = b; }
        else if (b < 384)  { src = msg_W;              dst = msgT;              R = 512;  tb = b - 128; }
        else if (b < 640)  { src = msg_W + 512 * 512;  dst = msgT + 512 * 512;  R = 512;  tb = b - 384; }
        else if (b < 1152) { src = upd_W;              dst = updT;              R = 1024; tb = b - 640; }
        else               { src = upd_W + 1024 * 512; dst = updT + 512 * 1024; R = 1024; tb = b - 1152; }
        const int rtiles = R >> 5;
        const int r0 = (tb % rtiles) * 32, c0 = (tb / rtiles) * 32;
        const int KT = R >> 6;
        __shared__ float t[32][33];
        const int tx = tid & 31, ty = tid >> 5;
        #pragma unroll
        for (int i = 0; i < 32; i += 8)
            t[ty + i][tx] = src[(size_t)(r0 + ty + i) * 512 + c0 + tx];
        __syncthreads();
        #pragma unroll
        for (int i = 0; i < 32; i += 8) {
            const int n = c0 + ty + i;   // packed row (n, 0..511)
            const int k = r0 + tx;       // packed col (k, 0..R-1)
            dst[(size_t)(((n >> 6) * KT + (k >> 6)) * 8 + ((k >> 3) & 7)) * 512
                + (n & 63) * 8 + (k & 7)] = (_Float16)t[tx][ty + i];
        }
    } else if (b < 1664 + castU) {
        const int i = (b - 1664) * 256 + tid;
        if (i < n4) {
            const float4 v = *(const float4*)(x + (size_t)i * 4);
            ushort4 s;
            union { _Float16 h; unsigned short u; } cv;
            cv.h = (_Float16)v.x; s.x = cv.u;
            cv.h = (_Float16)v.y; s.y = cv.u;
            cv.h = (_Float16)v.z; s.z = cv.u;
            cv.h = (_Float16)v.w; s.w = cv.u;
            const int f = i * 4;                 // flat half idx in [M,256]
            const int m = f >> 8, k = f & 255;
            *(ushort4*)((unsigned short*)xb
                + (size_t)(((m >> 6) * 4 + (k >> 6)) * 8 + ((k >> 3) & 7)) * 512
                + (m & 63) * 8 + (k & 7)) = s;
        }
    } else {
        const int e = (b - 1664 - castU) * 256 + tid;
        if (e < E) atomicAdd(&deg[eidx[E + e]], 1);
    }
}

// ---------------- CSR scan (single block) ----------------
__global__ __launch_bounds__(256) void scan_offsets(
    const int* __restrict__ deg, int* __restrict__ offs,
    int* __restrict__ cursor, int n)
{
    __shared__ int part[256];
    const int tid = threadIdx.x;
    const int chunk = (n + 255) / 256;
    const int base = tid * chunk;
    int sum = 0;
    for (int i = 0; i < chunk; ++i) {
        const int idx = base + i;
        if (idx < n) sum += deg[idx];
    }
    part[tid] = sum;
    __syncthreads();
    for (int off = 1; off < 256; off <<= 1) {
        const int v = (tid >= off) ? part[tid - off] : 0;
        __syncthreads();
        part[tid] += v;
        __syncthreads();
    }
    int run = (tid == 0) ? 0 : part[tid - 1];
    for (int i = 0; i < chunk; ++i) {
        const int idx = base + i;
        if (idx < n) { offs[idx] = run; cursor[idx] = run; run += deg[idx]; }
    }
    if (tid == 255) offs[n] = part[255];
}

// ------- aggregation: hmr row-major in, ag PACKED out. Column-quartered. -----
__global__ __launch_bounds__(256) void aggregate_f16(
    const _Float16* __restrict__ hmr, const int* __restrict__ offs,
    const int* __restrict__ srcs, _Float16* __restrict__ ag, int n)
{
    const int l16  = threadIdx.x & 15;
    const int node = blockIdx.x * 16 + (threadIdx.x >> 4);
    if (node >= n) return;
    const int c8 = blockIdx.y * 128 + l16 * 8;
    const int beg = offs[node], end = offs[node + 1];
    float a[8] = {};
    int j = beg;
    for (; j + 3 < end; j += 4) {
        const half8 v0 = *(const half8*)(hmr + (size_t)srcs[j]     * 512 + c8);
        const half8 v1 = *(const half8*)(hmr + (size_t)srcs[j + 1] * 512 + c8);
        const half8 v2 = *(const half8*)(hmr + (size_t)srcs[j + 2] * 512 + c8);
        const half8 v3 = *(const half8*)(hmr + (size_t)srcs[j + 3] * 512 + c8);
        #pragma unroll
        for (int i = 0; i < 8; ++i)
            a[i] += ((float)v0[i] + (float)v1[i]) + ((float)v2[i] + (float)v3[i]);
    }
    for (; j < end; ++j) {
        const half8 v = *(const half8*)(hmr + (size_t)srcs[j] * 512 + c8);
        #pragma unroll
        for (int i = 0; i < 8; ++i) a[i] += (float)v[i];
    }
    half8 o;
    #pragma unroll
    for (int i = 0; i < 8; ++i) o[i] = (_Float16)a[i];
    *(half8*)(ag + (size_t)(((node >> 6) * 8 + (c8 >> 6)) * 8 + ((c8 >> 3) & 7)) * 512
              + (node & 63) * 8) = o;
}

// ---------------- epilogue dot: out = h(packed) @ W_out + b_out --------------
__global__ __launch_bounds__(256) void out_dot(
    const _Float16* __restrict__ h, const float* __restrict__ Wout,
    const float* __restrict__ bout, float* __restrict__ out, int M)
{
    const int gid = blockIdx.x * 256 + threadIdx.x;
    const int node = gid >> 6;
    const int lane = gid & 63;
    if (node >= M) return;
    const half8 hv = *(const half8*)(h
        + (size_t)(((node >> 6) * 8 + (lane >> 3)) * 8 + (lane & 7)) * 512
        + (node & 63) * 8);
    const float4 w0 = *(const float4*)(Wout + lane * 8);
    const float4 w1 = *(const float4*)(Wout + lane * 8 + 4);
    float s = (float)hv[0] * w0.x + (float)hv[1] * w0.y
            + (float)hv[2] * w0.z + (float)hv[3] * w0.w
            + (float)hv[4] * w1.x + (float)hv[5] * w1.y
            + (float)hv[6] * w1.z + (float)hv[7] * w1.w;
    #pragma unroll
    for (int off = 32; off > 0; off >>= 1)
        s += __shfl_down(s, off);
    if (lane == 0) out[node] = s + bout[0];
}

extern "C" void kernel_launch(void* const* d_in, const int* in_sizes, int n_in,
                              void* d_out, int out_size, void* d_ws, size_t ws_size,
                              hipStream_t stream)
{
    const float* x     = (const float*)d_in[0];
    const int*   eidx  = (const int*)  d_in[1];
    const float* W_in  = (const float*)d_in[2];
    const float* b_in  = (const float*)d_in[3];
    const float* msg_W = (const float*)d_in[4];
    const float* msg_b = (const float*)d_in[5];
    const float* upd_W = (const float*)d_in[6];
    const float* upd_b = (const float*)d_in[7];
    const float* W_out = (const float*)d_in[8];
    const float* b_out = (const float*)d_in[9];

    const int IN = 256, H = 512;
    const int M = in_sizes[0] / IN;   // 10000
    const int E = in_sizes[1] / 2;    // 160000
    const int Mtiles = (M + 63) / 64;
    const size_t Mt64 = (size_t)Mtiles * 64;

    _Float16* xb   = (_Float16*)d_ws;           // packed [Mt64, 256]
    _Float16* B0   = xb + Mt64 * IN;            // packed or row-major [Mt64,512]
    _Float16* B1   = B0 + Mt64 * H;
    _Float16* B2   = B1 + Mt64 * H;             // packed aggr
    _Float16* WinT = B2 + Mt64 * H;             // packed [512,256]
    _Float16* msgT = WinT + (size_t)H * IN;     // packed [2][512,512]
    _Float16* updT = msgT + (size_t)2 * H * H;  // packed [2][512,1024]
    int* deg    = (int*)(updT + (size_t)2 * H * 2 * H);
    int* offs   = deg + M;
    int* cursor = offs + M + 1;
    int* srcs   = cursor + M;

    const dim3 blk(256);
    const int gemmBlocks = ((Mtiles + 7) / 8) * 64;
    const dim3 aggrGrid((M + 15) / 16, 4);

    const int n4 = M * IN / 4;
    const int castU = (n4 + 255) / 256;
    const int countU = (E + 255) / 256;
    const int fillU = countU;

    hipMemsetAsync(deg, 0, (size_t)M * sizeof(int), stream);
    prep<<<dim3(1664 + castU + countU), blk, 0, stream>>>(
        W_in, WinT, msg_W, msgT, upd_W, updT, x, xb, eidx, deg, E, n4, M);
    scan_offsets<<<dim3(1), blk, 0, stream>>>(deg, offs, cursor, M);
    // CSR fill || in-GEMM (independent of each other)
    fill_ingemm<<<dim3(fillU + gemmBlocks), blk, 0, stream>>>(
        eidx, cursor, srcs, E, xb, WinT, b_in, B0, M, Mtiles);

    // layer 0
    gemm_f16<<<dim3(gemmBlocks), blk, 0, stream>>>(B0, 8, nullptr, 0,
        msgT, 8, 0, msg_b, B1, M, Mtiles, 0, 1);                 // msg -> B1 row-major
    aggregate_f16<<<aggrGrid, blk, 0, stream>>>(B1, offs, srcs, B2, M);
    gemm_f16<<<dim3(gemmBlocks), blk, 0, stream>>>(B0, 8, B2, 8,
        updT, 16, 8, upd_b, B1, M, Mtiles, 1, 1);                // upd -> B1 packed
    // layer 1
    gemm_f16<<<dim3(gemmBlocks), blk, 0, stream>>>(B1, 8, nullptr, 0,
        msgT + 512 * 512, 8, 0, msg_b + 512, B0, M, Mtiles, 0, 1);
    aggregate_f16<<<aggrGrid, blk, 0, stream>>>(B0, offs, srcs, B2, M);
    gemm_f16<<<dim3(gemmBlocks), blk, 0, stream>>>(B1, 8, B2, 8,
        updT + 512 * 1024, 16, 8, upd_b + 512, B0, M, Mtiles, 1, 1);

    out_dot<<<dim3((M * 64 + 255) / 256), blk, 0, stream>>>(
        B0, W_out, b_out, (float*)d_out, M);
}

// Round 11
// 244.768 us; speedup vs baseline: 1.1035x; 1.1035x over previous
//
#include <hip/hip_runtime.h>

// MPNN regression. R11: R8's GEMM verbatim (single-buffer, 16 KB LDS, two
// __syncthreads per kt — best measured; R9/R10 pipelining exotica regressed
// via LDS-occupancy loss + compiler-forced vmcnt serialization). Stream ops
// 13 -> 11: prep absorbs count_deg, fill_csr fuses with in-GEMM, and out_dot
// fuses into upd1's epilogue (skip C write, quad-reduce + atomicAdd to d_out).
// Packed tile format P[mt][kt][ch][row][8] for all GEMM operands (R8).

typedef _Float16 half8 __attribute__((ext_vector_type(8)));
typedef float float4v __attribute__((ext_vector_type(4)));

#define ASYNC_COPY16(gptr, lptr)                                              \
    __builtin_amdgcn_global_load_lds(                                         \
        (const __attribute__((address_space(1))) void*)(gptr),                \
        (__attribute__((address_space(3))) void*)(lptr), 16, 0, 0)

// packed addr (halfs) for element (m,k) of a [*,K] matrix, KT = K/64:
//   ((m/64*KT + k/64)*8 + (k%64)/8)*512 + (m%64)*8 + k%8

// ---------------- fp16 MFMA GEMM body, packed inputs (R8 structure) ----------
// C = relu(A1@W1 [+ A2@W2] + bias). Block 64x64, 4 waves of 32x32, BK=64.
// outp != nullptr: fused final dot — skip C, emit atomicAdd(out[row], ...).
__device__ __forceinline__ void gemm_body(int id,
    const _Float16* __restrict__ A1, int KT1,
    const _Float16* __restrict__ A2, int KT2,
    const _Float16* __restrict__ Wt, int KTw, int ktw2,
    const float* __restrict__ bias, _Float16* __restrict__ C,
    int M, int Mtiles, int packC, int do_relu,
    const float* __restrict__ Wout, const float* __restrict__ bout,
    float* __restrict__ outp)
{
    __shared__ _Float16 As[4096];   // [ch 0..7][row 0..63][8]  8 KB
    __shared__ _Float16 Bs[4096];

    const int tid  = threadIdx.x;
    const int wave = tid >> 6, lane = tid & 63;

    // swizzle: 8 pn-panels of one mt on consecutive ids == cxcd (mod 8)
    const int cxcd = id & 7, j = id >> 3;
    const int mt = cxcd + 8 * (j >> 3);
    if (mt >= Mtiles) return;
    const int pn = j & 7;
    const int bm = mt * 64, bn = pn * 64;

    const int wr = (wave >> 1) * 32, wc = (wave & 1) * 32;
    const int m16 = lane & 15, quad = lane >> 4;

    float4v acc[2][2] = {};
    float bv[2];
    #pragma unroll
    for (int jj = 0; jj < 2; ++jj) bv[jj] = bias[bn + wc + jj * 16 + m16];

    for (int pass = 0; pass < 2; ++pass) {
        const _Float16* __restrict__ A = pass ? A2 : A1;
        if (A == nullptr) continue;
        const int KTa  = pass ? KT2 : KT1;
        const int ktw0 = pass ? ktw2 : 0;

        for (int kt = 0; kt < KTa; ++kt) {
            const _Float16* Ab = A  + (size_t)(mt * KTa + kt) * 4096;
            const _Float16* Wb = Wt + (size_t)(pn * KTw + ktw0 + kt) * 4096;
            #pragma unroll
            for (int t = 0; t < 2; ++t) {
                const int q = t * 4 + wave;   // 1 KB chunk; dest = base + lane*16
                ASYNC_COPY16(Ab + q * 512 + lane * 8, (char*)As + q * 1024);
                ASYNC_COPY16(Wb + q * 512 + lane * 8, (char*)Bs + q * 1024);
            }
            __syncthreads();
            #pragma unroll
            for (int c = 0; c < 2; ++c) {
                half8 af[2], bf[2];
                #pragma unroll
                for (int i2 = 0; i2 < 2; ++i2)
                    af[i2] = *(const half8*)
                        &As[((c * 4 + quad) * 64 + wr + i2 * 16 + m16) * 8];
                #pragma unroll
                for (int j2 = 0; j2 < 2; ++j2)
                    bf[j2] = *(const half8*)
                        &Bs[((c * 4 + quad) * 64 + wc + j2 * 16 + m16) * 8];
                #pragma unroll
                for (int i2 = 0; i2 < 2; ++i2)
                    #pragma unroll
                    for (int j2 = 0; j2 < 2; ++j2)
                        acc[i2][j2] = __builtin_amdgcn_mfma_f32_16x16x32_f16(
                            af[i2], bf[j2], acc[i2][j2], 0, 0, 0);
            }
            __syncthreads();
        }
    }

    if (outp) {
        // fused epilogue: out[row] += sum_cols relu(v) * Wout[col]  (+ b_out once)
        #pragma unroll
        for (int i = 0; i < 2; ++i)
            #pragma unroll
            for (int rg = 0; rg < 4; ++rg) {
                const int r2 = wr + i * 16 + quad * 4 + rg;
                const int row = bm + r2;
                float pr = 0.f;
                #pragma unroll
                for (int j2 = 0; j2 < 2; ++j2) {
                    float v = fmaxf(acc[i][j2][rg] + bv[j2], 0.f);
                    pr += v * Wout[bn + wc + j2 * 16 + m16];
                }
                pr += __shfl_xor(pr, 1);   // reduce 16 lanes of the quad
                pr += __shfl_xor(pr, 2);
                pr += __shfl_xor(pr, 4);
                pr += __shfl_xor(pr, 8);
                if (m16 == 0 && row < M)
                    atomicAdd(&outp[row],
                              pr + ((pn == 0 && wc == 0) ? bout[0] : 0.f));
            }
        return;
    }

    // epilogue: D layout col=lane&15, row=quad*4+reg
    #pragma unroll
    for (int i = 0; i < 2; ++i)
        #pragma unroll
        for (int rg = 0; rg < 4; ++rg) {
            const int r2 = wr + i * 16 + quad * 4 + rg;
            const int row = bm + r2;
            if (row >= M) continue;
            #pragma unroll
            for (int j2 = 0; j2 < 2; ++j2) {
                float v = acc[i][j2][rg] + bv[j2];
                if (do_relu) v = fmaxf(v, 0.f);
                const int coff = wc + j2 * 16 + m16;
                if (packC) {
                    C[(size_t)((mt * 8 + pn) * 8 + (coff >> 3)) * 512
                      + r2 * 8 + (coff & 7)] = (_Float16)v;
                } else {
                    C[(size_t)row * 512 + bn + coff] = (_Float16)v;
                }
            }
        }
}

__global__ __launch_bounds__(256) void gemm_f16(
    const _Float16* __restrict__ A1, int KT1,
    const _Float16* __restrict__ A2, int KT2,
    const _Float16* __restrict__ Wt, int KTw, int ktw2,
    const float* __restrict__ bias, _Float16* __restrict__ C,
    int M, int Mtiles, int packC, int do_relu,
    const float* Wout, const float* bout, float* outp)
{
    gemm_body(blockIdx.x, A1, KT1, A2, KT2, Wt, KTw, ktw2,
              bias, C, M, Mtiles, packC, do_relu, Wout, bout, outp);
}

// ------- fused: CSR fill (independent) || in-GEMM h0 = relu(x@W_in+b) -------
__global__ __launch_bounds__(256) void fill_ingemm(
    const int* __restrict__ eidx, int* __restrict__ cursor,
    int* __restrict__ srcs, int E,
    const _Float16* __restrict__ xb, const _Float16* __restrict__ WinT,
    const float* __restrict__ b_in, _Float16* __restrict__ B0,
    int M, int Mtiles)
{
    const int fillU = (E + 255) >> 8;
    if ((int)blockIdx.x < fillU) {
        const int e = blockIdx.x * 256 + threadIdx.x;
        if (e < E) {
            const int pos = atomicAdd(&cursor[eidx[E + e]], 1);
            srcs[pos] = eidx[e];
        }
        return;
    }
    gemm_body(blockIdx.x - fillU, xb, 4, nullptr, 0, WinT, 4, 0,
              b_in, B0, M, Mtiles, 1, 1, nullptr, nullptr, nullptr);
}

// ------- prep: weight transpose->packed + x cast->packed + count_deg -------
// (deg zeroed by a prior hipMemsetAsync on the same stream)
__global__ __launch_bounds__(256) void prep(
    const float* __restrict__ W_in,  _Float16* __restrict__ WinT,
    const float* __restrict__ msg_W, _Float16* __restrict__ msgT,
    const float* __restrict__ upd_W, _Float16* __restrict__ updT,
    const float* __restrict__ x,     _Float16* __restrict__ xb,
    const int* __restrict__ eidx, int* __restrict__ deg, int E,
    int n4, int M)
{
    const int b = blockIdx.x;
    const int tid = threadIdx.x;
    const int castU = (n4 + 255) >> 8;
    if (b < 1664) {
        const float* src; _Float16* dst; int R; int tb;
        if (b < 128)       { src = W_in;               dst = WinT;              R = 256;  tb = b; }
        else if (b < 384)  { src = msg_W;              dst = msgT;              R = 512;  tb = b - 128; }
        else if (b < 640)  { src = msg_W + 512 * 512;  dst = msgT + 512 * 512;  R = 512;  tb = b - 384; }
        else if (b < 1152) { src = upd_W;              dst = updT;              R = 1024; tb = b - 640; }
        else               { src = upd_W + 1024 * 512; dst = updT + 512 * 1024; R = 1024; tb = b - 1152; }
        const int rtiles = R >> 5;
        const int r0 = (tb % rtiles) * 32, c0 = (tb / rtiles) * 32;
        const int KT = R >> 6;
        __shared__ float t[32][33];
        const int tx = tid & 31, ty = tid >> 5;
        #pragma unroll
        for (int i = 0; i < 32; i += 8)
            t[ty + i][tx] = src[(size_t)(r0 + ty + i) * 512 + c0 + tx];
        __syncthreads();
        #pragma unroll
        for (int i = 0; i < 32; i += 8) {
            const int n = c0 + ty + i;   // packed row (n, 0..511)
            const int k = r0 + tx;       // packed col (k, 0..R-1)
            dst[(size_t)(((n >> 6) * KT + (k >> 6)) * 8 + ((k >> 3) & 7)) * 512
                + (n & 63) * 8 + (k & 7)] = (_Float16)t[tx][ty + i];
        }
    } else if (b < 1664 + castU) {
        const int i = (b - 1664) * 256 + tid;
        if (i < n4) {
            const float4 v = *(const float4*)(x + (size_t)i * 4);
            ushort4 s;
            union { _Float16 h; unsigned short u; } cv;
            cv.h = (_Float16)v.x; s.x = cv.u;
            cv.h = (_Float16)v.y; s.y = cv.u;
            cv.h = (_Float16)v.z; s.z = cv.u;
            cv.h = (_Float16)v.w; s.w = cv.u;
            const int f = i * 4;                 // flat half idx in [M,256]
            const int m = f >> 8, k = f & 255;
            *(ushort4*)((unsigned short*)xb
                + (size_t)(((m >> 6) * 4 + (k >> 6)) * 8 + ((k >> 3) & 7)) * 512
                + (m & 63) * 8 + (k & 7)) = s;
        }
    } else {
        const int e = (b - 1664 - castU) * 256 + tid;
        if (e < E) atomicAdd(&deg[eidx[E + e]], 1);
    }
}

// ---------------- CSR scan (single block) ----------------
__global__ __launch_bounds__(256) void scan_offsets(
    const int* __restrict__ deg, int* __restrict__ offs,
    int* __restrict__ cursor, int n)
{
    __shared__ int part[256];
    const int tid = threadIdx.x;
    const int chunk = (n + 255) / 256;
    const int base = tid * chunk;
    int sum = 0;
    for (int i = 0; i < chunk; ++i) {
        const int idx = base + i;
        if (idx < n) sum += deg[idx];
    }
    part[tid] = sum;
    __syncthreads();
    for (int off = 1; off < 256; off <<= 1) {
        const int v = (tid >= off) ? part[tid - off] : 0;
        __syncthreads();
        part[tid] += v;
        __syncthreads();
    }
    int run = (tid == 0) ? 0 : part[tid - 1];
    for (int i = 0; i < chunk; ++i) {
        const int idx = base + i;
        if (idx < n) { offs[idx] = run; cursor[idx] = run; run += deg[idx]; }
    }
    if (tid == 255) offs[n] = part[255];
}

// ------- aggregation: hmr row-major in, ag PACKED out. Column-quartered. -----
__global__ __launch_bounds__(256) void aggregate_f16(
    const _Float16* __restrict__ hmr, const int* __restrict__ offs,
    const int* __restrict__ srcs, _Float16* __restrict__ ag, int n)
{
    const int l16  = threadIdx.x & 15;
    const int node = blockIdx.x * 16 + (threadIdx.x >> 4);
    if (node >= n) return;
    const int c8 = blockIdx.y * 128 + l16 * 8;
    const int beg = offs[node], end = offs[node + 1];
    float a[8] = {};
    int j = beg;
    for (; j + 3 < end; j += 4) {
        const half8 v0 = *(const half8*)(hmr + (size_t)srcs[j]     * 512 + c8);
        const half8 v1 = *(const half8*)(hmr + (size_t)srcs[j + 1] * 512 + c8);
        const half8 v2 = *(const half8*)(hmr + (size_t)srcs[j + 2] * 512 + c8);
        const half8 v3 = *(const half8*)(hmr + (size_t)srcs[j + 3] * 512 + c8);
        #pragma unroll
        for (int i = 0; i < 8; ++i)
            a[i] += ((float)v0[i] + (float)v1[i]) + ((float)v2[i] + (float)v3[i]);
    }
    for (; j < end; ++j) {
        const half8 v = *(const half8*)(hmr + (size_t)srcs[j] * 512 + c8);
        #pragma unroll
        for (int i = 0; i < 8; ++i) a[i] += (float)v[i];
    }
    half8 o;
    #pragma unroll
    for (int i = 0; i < 8; ++i) o[i] = (_Float16)a[i];
    *(half8*)(ag + (size_t)(((node >> 6) * 8 + (c8 >> 6)) * 8 + ((c8 >> 3) & 7)) * 512
              + (node & 63) * 8) = o;
}

extern "C" void kernel_launch(void* const* d_in, const int* in_sizes, int n_in,
                              void* d_out, int out_size, void* d_ws, size_t ws_size,
                              hipStream_t stream)
{
    const float* x     = (const float*)d_in[0];
    const int*   eidx  = (const int*)  d_in[1];
    const float* W_in  = (const float*)d_in[2];
    const float* b_in  = (const float*)d_in[3];
    const float* msg_W = (const float*)d_in[4];
    const float* msg_b = (const float*)d_in[5];
    const float* upd_W = (const float*)d_in[6];
    const float* upd_b = (const float*)d_in[7];
    const float* W_out = (const float*)d_in[8];
    const float* b_out = (const float*)d_in[9];

    const int IN = 256, H = 512;
    const int M = in_sizes[0] / IN;   // 10000
    const int E = in_sizes[1] / 2;    // 160000
    const int Mtiles = (M + 63) / 64;
    const size_t Mt64 = (size_t)Mtiles * 64;

    _Float16* xb   = (_Float16*)d_ws;           // packed [Mt64, 256]
    _Float16* B0   = xb + Mt64 * IN;            // packed or row-major [Mt64,512]
    _Float16* B1   = B0 + Mt64 * H;
    _Float16* B2   = B1 + Mt64 * H;             // packed aggr
    _Float16* WinT = B2 + Mt64 * H;             // packed [512,256]
    _Float16* msgT = WinT + (size_t)H * IN;     // packed [2][512,512]
    _Float16* updT = msgT + (size_t)2 * H * H;  // packed [2][512,1024]
    int* deg    = (int*)(updT + (size_t)2 * H * 2 * H);
    int* offs   = deg + M;
    int* cursor = offs + M + 1;
    int* srcs   = cursor + M;

    const dim3 blk(256);
    const int gemmBlocks = ((Mtiles + 7) / 8) * 64;
    const dim3 aggrGrid((M + 15) / 16, 4);

    const int n4 = M * IN / 4;
    const int castU = (n4 + 255) / 256;
    const int countU = (E + 255) / 256;
    const int fillU = countU;

    hipMemsetAsync(deg, 0, (size_t)M * sizeof(int), stream);
    hipMemsetAsync(d_out, 0, (size_t)out_size * sizeof(float), stream);
    prep<<<dim3(1664 + castU + countU), blk, 0, stream>>>(
        W_in, WinT, msg_W, msgT, upd_W, updT, x, xb, eidx, deg, E, n4, M);
    scan_offsets<<<dim3(1), blk, 0, stream>>>(deg, offs, cursor, M);
    // CSR fill || in-GEMM (independent of each other)
    fill_ingemm<<<dim3(fillU + gemmBlocks), blk, 0, stream>>>(
        eidx, cursor, srcs, E, xb, WinT, b_in, B0, M, Mtiles);

    // layer 0
    gemm_f16<<<dim3(gemmBlocks), blk, 0, stream>>>(B0, 8, nullptr, 0,
        msgT, 8, 0, msg_b, B1, M, Mtiles, 0, 1,
        nullptr, nullptr, nullptr);                              // msg -> B1 row-major
    aggregate_f16<<<aggrGrid, blk, 0, stream>>>(B1, offs, srcs, B2, M);
    gemm_f16<<<dim3(gemmBlocks), blk, 0, stream>>>(B0, 8, B2, 8,
        updT, 16, 8, upd_b, B1, M, Mtiles, 1, 1,
        nullptr, nullptr, nullptr);                              // upd -> B1 packed
    // layer 1
    gemm_f16<<<dim3(gemmBlocks), blk, 0, stream>>>(B1, 8, nullptr, 0,
        msgT + 512 * 512, 8, 0, msg_b + 512, B0, M, Mtiles, 0, 1,
        nullptr, nullptr, nullptr);                              // msg -> B0 row-major
    aggregate_f16<<<aggrGrid, blk, 0, stream>>>(B0, offs, srcs, B2, M);
    // upd l1 with FUSED final dot: no C write, atomicAdd into d_out
    gemm_f16<<<dim3(gemmBlocks), blk, 0, stream>>>(B1, 8, B2, 8,
        updT + 512 * 1024, 16, 8, upd_b + 512, nullptr, M, Mtiles, 1, 1,
        W_out, b_out, (float*)d_out);
}

// Round 12
// 240.377 us; speedup vs baseline: 1.1236x; 1.0183x over previous
//
#include <hip/hip_runtime.h>

// MPNN regression. R12: stream ops 11 -> 10 — deg array eliminated; the
// degree histogram lives in d_out (which the single memset zeroes anyway for
// the fused final-dot atomics). prep counts into (int*)d_out, scan consumes,
// agg0 re-zeroes d_out (after scan, before upd1's atomicAdds). GEMM = R8
// structure verbatim (best measured). Packed tiles P[mt][kt][ch][row][8].

typedef _Float16 half8 __attribute__((ext_vector_type(8)));
typedef float float4v __attribute__((ext_vector_type(4)));

#define ASYNC_COPY16(gptr, lptr)                                              \
    __builtin_amdgcn_global_load_lds(                                         \
        (const __attribute__((address_space(1))) void*)(gptr),                \
        (__attribute__((address_space(3))) void*)(lptr), 16, 0, 0)

// packed addr (halfs) for element (m,k) of a [*,K] matrix, KT = K/64:
//   ((m/64*KT + k/64)*8 + (k%64)/8)*512 + (m%64)*8 + k%8

// ---------------- fp16 MFMA GEMM body, packed inputs (R8 structure) ----------
// C = relu(A1@W1 [+ A2@W2] + bias). Block 64x64, 4 waves of 32x32, BK=64.
// outp != nullptr: fused final dot — skip C, emit atomicAdd(out[row], ...).
__device__ __forceinline__ void gemm_body(int id,
    const _Float16* __restrict__ A1, int KT1,
    const _Float16* __restrict__ A2, int KT2,
    const _Float16* __restrict__ Wt, int KTw, int ktw2,
    const float* __restrict__ bias, _Float16* __restrict__ C,
    int M, int Mtiles, int packC, int do_relu,
    const float* __restrict__ Wout, const float* __restrict__ bout,
    float* __restrict__ outp)
{
    __shared__ _Float16 As[4096];   // [ch 0..7][row 0..63][8]  8 KB
    __shared__ _Float16 Bs[4096];

    const int tid  = threadIdx.x;
    const int wave = tid >> 6, lane = tid & 63;

    // swizzle: 8 pn-panels of one mt on consecutive ids == cxcd (mod 8)
    const int cxcd = id & 7, j = id >> 3;
    const int mt = cxcd + 8 * (j >> 3);
    if (mt >= Mtiles) return;
    const int pn = j & 7;
    const int bm = mt * 64, bn = pn * 64;

    const int wr = (wave >> 1) * 32, wc = (wave & 1) * 32;
    const int m16 = lane & 15, quad = lane >> 4;

    float4v acc[2][2] = {};
    float bv[2];
    #pragma unroll
    for (int jj = 0; jj < 2; ++jj) bv[jj] = bias[bn + wc + jj * 16 + m16];

    for (int pass = 0; pass < 2; ++pass) {
        const _Float16* __restrict__ A = pass ? A2 : A1;
        if (A == nullptr) continue;
        const int KTa  = pass ? KT2 : KT1;
        const int ktw0 = pass ? ktw2 : 0;

        for (int kt = 0; kt < KTa; ++kt) {
            const _Float16* Ab = A  + (size_t)(mt * KTa + kt) * 4096;
            const _Float16* Wb = Wt + (size_t)(pn * KTw + ktw0 + kt) * 4096;
            #pragma unroll
            for (int t = 0; t < 2; ++t) {
                const int q = t * 4 + wave;   // 1 KB chunk; dest = base + lane*16
                ASYNC_COPY16(Ab + q * 512 + lane * 8, (char*)As + q * 1024);
                ASYNC_COPY16(Wb + q * 512 + lane * 8, (char*)Bs + q * 1024);
            }
            __syncthreads();
            #pragma unroll
            for (int c = 0; c < 2; ++c) {
                half8 af[2], bf[2];
                #pragma unroll
                for (int i2 = 0; i2 < 2; ++i2)
                    af[i2] = *(const half8*)
                        &As[((c * 4 + quad) * 64 + wr + i2 * 16 + m16) * 8];
                #pragma unroll
                for (int j2 = 0; j2 < 2; ++j2)
                    bf[j2] = *(const half8*)
                        &Bs[((c * 4 + quad) * 64 + wc + j2 * 16 + m16) * 8];
                #pragma unroll
                for (int i2 = 0; i2 < 2; ++i2)
                    #pragma unroll
                    for (int j2 = 0; j2 < 2; ++j2)
                        acc[i2][j2] = __builtin_amdgcn_mfma_f32_16x16x32_f16(
                            af[i2], bf[j2], acc[i2][j2], 0, 0, 0);
            }
            __syncthreads();
        }
    }

    if (outp) {
        // fused epilogue: out[row] += sum_cols relu(v) * Wout[col]  (+ b_out once)
        #pragma unroll
        for (int i = 0; i < 2; ++i)
            #pragma unroll
            for (int rg = 0; rg < 4; ++rg) {
                const int r2 = wr + i * 16 + quad * 4 + rg;
                const int row = bm + r2;
                float pr = 0.f;
                #pragma unroll
                for (int j2 = 0; j2 < 2; ++j2) {
                    float v = fmaxf(acc[i][j2][rg] + bv[j2], 0.f);
                    pr += v * Wout[bn + wc + j2 * 16 + m16];
                }
                pr += __shfl_xor(pr, 1);   // reduce the 16 lanes of the quad
                pr += __shfl_xor(pr, 2);
                pr += __shfl_xor(pr, 4);
                pr += __shfl_xor(pr, 8);
                if (m16 == 0 && row < M)
                    atomicAdd(&outp[row],
                              pr + ((pn == 0 && wc == 0) ? bout[0] : 0.f));
            }
        return;
    }

    // epilogue: D layout col=lane&15, row=quad*4+reg
    #pragma unroll
    for (int i = 0; i < 2; ++i)
        #pragma unroll
        for (int rg = 0; rg < 4; ++rg) {
            const int r2 = wr + i * 16 + quad * 4 + rg;
            const int row = bm + r2;
            if (row >= M) continue;
            #pragma unroll
            for (int j2 = 0; j2 < 2; ++j2) {
                float v = acc[i][j2][rg] + bv[j2];
                if (do_relu) v = fmaxf(v, 0.f);
                const int coff = wc + j2 * 16 + m16;
                if (packC) {
                    C[(size_t)((mt * 8 + pn) * 8 + (coff >> 3)) * 512
                      + r2 * 8 + (coff & 7)] = (_Float16)v;
                } else {
                    C[(size_t)row * 512 + bn + coff] = (_Float16)v;
                }
            }
        }
}

__global__ __launch_bounds__(256) void gemm_f16(
    const _Float16* __restrict__ A1, int KT1,
    const _Float16* __restrict__ A2, int KT2,
    const _Float16* __restrict__ Wt, int KTw, int ktw2,
    const float* __restrict__ bias, _Float16* __restrict__ C,
    int M, int Mtiles, int packC, int do_relu,
    const float* Wout, const float* bout, float* outp)
{
    gemm_body(blockIdx.x, A1, KT1, A2, KT2, Wt, KTw, ktw2,
              bias, C, M, Mtiles, packC, do_relu, Wout, bout, outp);
}

// ------- fused: CSR fill (independent) || in-GEMM h0 = relu(x@W_in+b) -------
__global__ __launch_bounds__(256) void fill_ingemm(
    const int* __restrict__ eidx, int* __restrict__ cursor,
    int* __restrict__ srcs, int E,
    const _Float16* __restrict__ xb, const _Float16* __restrict__ WinT,
    const float* __restrict__ b_in, _Float16* __restrict__ B0,
    int M, int Mtiles)
{
    const int fillU = (E + 255) >> 8;
    if ((int)blockIdx.x < fillU) {
        const int e = blockIdx.x * 256 + threadIdx.x;
        if (e < E) {
            const int pos = atomicAdd(&cursor[eidx[E + e]], 1);
            srcs[pos] = eidx[e];
        }
        return;
    }
    gemm_body(blockIdx.x - fillU, xb, 4, nullptr, 0, WinT, 4, 0,
              b_in, B0, M, Mtiles, 1, 1, nullptr, nullptr, nullptr);
}

// ------- prep: weight transpose->packed + x cast->packed + count_deg -------
// deg == (int*)d_out, zeroed by the single hipMemsetAsync(d_out) before this.
__global__ __launch_bounds__(256) void prep(
    const float* __restrict__ W_in,  _Float16* __restrict__ WinT,
    const float* __restrict__ msg_W, _Float16* __restrict__ msgT,
    const float* __restrict__ upd_W, _Float16* __restrict__ updT,
    const float* __restrict__ x,     _Float16* __restrict__ xb,
    const int* __restrict__ eidx, int* __restrict__ deg, int E,
    int n4, int M)
{
    const int b = blockIdx.x;
    const int tid = threadIdx.x;
    const int castU = (n4 + 255) >> 8;
    if (b < 1664) {
        const float* src; _Float16* dst; int R; int tb;
        if (b < 128)       { src = W_in;               dst = WinT;              R = 256;  tb = b; }
        else if (b < 384)  { src = msg_W;              dst = msgT;              R = 512;  tb = b - 128; }
        else if (b < 640)  { src = msg_W + 512 * 512;  dst = msgT + 512 * 512;  R = 512;  tb = b - 384; }
        else if (b < 1152) { src = upd_W;              dst = updT;              R = 1024; tb = b - 640; }
        else               { src = upd_W + 1024 * 512; dst = updT + 512 * 1024; R = 1024; tb = b - 1152; }
        const int rtiles = R >> 5;
        const int r0 = (tb % rtiles) * 32, c0 = (tb / rtiles) * 32;
        const int KT = R >> 6;
        __shared__ float t[32][33];
        const int tx = tid & 31, ty = tid >> 5;
        #pragma unroll
        for (int i = 0; i < 32; i += 8)
            t[ty + i][tx] = src[(size_t)(r0 + ty + i) * 512 + c0 + tx];
        __syncthreads();
        #pragma unroll
        for (int i = 0; i < 32; i += 8) {
            const int n = c0 + ty + i;   // packed row (n, 0..511)
            const int k = r0 + tx;       // packed col (k, 0..R-1)
            dst[(size_t)(((n >> 6) * KT + (k >> 6)) * 8 + ((k >> 3) & 7)) * 512
                + (n & 63) * 8 + (k & 7)] = (_Float16)t[tx][ty + i];
        }
    } else if (b < 1664 + castU) {
        const int i = (b - 1664) * 256 + tid;
        if (i < n4) {
            const float4 v = *(const float4*)(x + (size_t)i * 4);
            ushort4 s;
            union { _Float16 h; unsigned short u; } cv;
            cv.h = (_Float16)v.x; s.x = cv.u;
            cv.h = (_Float16)v.y; s.y = cv.u;
            cv.h = (_Float16)v.z; s.z = cv.u;
            cv.h = (_Float16)v.w; s.w = cv.u;
            const int f = i * 4;                 // flat half idx in [M,256]
            const int m = f >> 8, k = f & 255;
            *(ushort4*)((unsigned short*)xb
                + (size_t)(((m >> 6) * 4 + (k >> 6)) * 8 + ((k >> 3) & 7)) * 512
                + (m & 63) * 8 + (k & 7)) = s;
        }
    } else {
        const int e = (b - 1664 - castU) * 256 + tid;
        if (e < E) atomicAdd(&deg[eidx[E + e]], 1);
    }
}

// ---------------- CSR scan (single block); deg == (int*)d_out ----------------
__global__ __launch_bounds__(256) void scan_offsets(
    const int* __restrict__ deg, int* __restrict__ offs,
    int* __restrict__ cursor, int n)
{
    __shared__ int part[256];
    const int tid = threadIdx.x;
    const int chunk = (n + 255) / 256;
    const int base = tid * chunk;
    int sum = 0;
    for (int i = 0; i < chunk; ++i) {
        const int idx = base + i;
        if (idx < n) sum += deg[idx];
    }
    part[tid] = sum;
    __syncthreads();
    for (int off = 1; off < 256; off <<= 1) {
        const int v = (tid >= off) ? part[tid - off] : 0;
        __syncthreads();
        part[tid] += v;
        __syncthreads();
    }
    int run = (tid == 0) ? 0 : part[tid - 1];
    for (int i = 0; i < chunk; ++i) {
        const int idx = base + i;
        if (idx < n) { offs[idx] = run; cursor[idx] = run; run += deg[idx]; }
    }
    if (tid == 255) offs[n] = part[255];
}

// ------- aggregation: hmr row-major in, ag PACKED out. Column-quartered. -----
// zbuf != nullptr: blocks (y==0, x<ceil(zN/256)) also zero zbuf (d_out reuse:
// runs after scan consumed the degree histogram, before upd1's atomicAdds).
__global__ __launch_bounds__(256) void aggregate_f16(
    const _Float16* __restrict__ hmr, const int* __restrict__ offs,
    const int* __restrict__ srcs, _Float16* __restrict__ ag, int n,
    float* __restrict__ zbuf, int zN)
{
    if (zbuf && blockIdx.y == 0) {
        const int zi = blockIdx.x * 256 + threadIdx.x;
        if (zi < zN) zbuf[zi] = 0.f;
    }
    const int l16  = threadIdx.x & 15;
    const int node = blockIdx.x * 16 + (threadIdx.x >> 4);
    if (node >= n) return;
    const int c8 = blockIdx.y * 128 + l16 * 8;
    const int beg = offs[node], end = offs[node + 1];
    float a[8] = {};
    int j = beg;
    for (; j + 3 < end; j += 4) {
        const half8 v0 = *(const half8*)(hmr + (size_t)srcs[j]     * 512 + c8);
        const half8 v1 = *(const half8*)(hmr + (size_t)srcs[j + 1] * 512 + c8);
        const half8 v2 = *(const half8*)(hmr + (size_t)srcs[j + 2] * 512 + c8);
        const half8 v3 = *(const half8*)(hmr + (size_t)srcs[j + 3] * 512 + c8);
        #pragma unroll
        for (int i = 0; i < 8; ++i)
            a[i] += ((float)v0[i] + (float)v1[i]) + ((float)v2[i] + (float)v3[i]);
    }
    for (; j < end; ++j) {
        const half8 v = *(const half8*)(hmr + (size_t)srcs[j] * 512 + c8);
        #pragma unroll
        for (int i = 0; i < 8; ++i) a[i] += (float)v[i];
    }
    half8 o;
    #pragma unroll
    for (int i = 0; i < 8; ++i) o[i] = (_Float16)a[i];
    *(half8*)(ag + (size_t)(((node >> 6) * 8 + (c8 >> 6)) * 8 + ((c8 >> 3) & 7)) * 512
              + (node & 63) * 8) = o;
}

extern "C" void kernel_launch(void* const* d_in, const int* in_sizes, int n_in,
                              void* d_out, int out_size, void* d_ws, size_t ws_size,
                              hipStream_t stream)
{
    const float* x     = (const float*)d_in[0];
    const int*   eidx  = (const int*)  d_in[1];
    const float* W_in  = (const float*)d_in[2];
    const float* b_in  = (const float*)d_in[3];
    const float* msg_W = (const float*)d_in[4];
    const float* msg_b = (const float*)d_in[5];
    const float* upd_W = (const float*)d_in[6];
    const float* upd_b = (const float*)d_in[7];
    const float* W_out = (const float*)d_in[8];
    const float* b_out = (const float*)d_in[9];

    const int IN = 256, H = 512;
    const int M = in_sizes[0] / IN;   // 10000
    const int E = in_sizes[1] / 2;    // 160000
    const int Mtiles = (M + 63) / 64;
    const size_t Mt64 = (size_t)Mtiles * 64;

    _Float16* xb   = (_Float16*)d_ws;           // packed [Mt64, 256]
    _Float16* B0   = xb + Mt64 * IN;            // packed or row-major [Mt64,512]
    _Float16* B1   = B0 + Mt64 * H;
    _Float16* B2   = B1 + Mt64 * H;             // packed aggr
    _Float16* WinT = B2 + Mt64 * H;             // packed [512,256]
    _Float16* msgT = WinT + (size_t)H * IN;     // packed [2][512,512]
    _Float16* updT = msgT + (size_t)2 * H * H;  // packed [2][512,1024]
    int* offs   = (int*)(updT + (size_t)2 * H * 2 * H);   // [M+1]
    int* cursor = offs + M + 1;                 // [M]
    int* srcs   = cursor + M;                   // [E]
    int* deg    = (int*)d_out;                  // degree histogram lives in d_out

    const dim3 blk(256);
    const int gemmBlocks = ((Mtiles + 7) / 8) * 64;
    const dim3 aggrGrid((M + 15) / 16, 4);

    const int n4 = M * IN / 4;
    const int castU = (n4 + 255) / 256;
    const int countU = (E + 255) / 256;
    const int fillU = countU;

    // single memset: zeroes d_out == the degree histogram (and the final
    // accumulator, which agg0 re-zeroes after scan consumes the counts)
    hipMemsetAsync(d_out, 0, (size_t)out_size * sizeof(float), stream);
    prep<<<dim3(1664 + castU + countU), blk, 0, stream>>>(
        W_in, WinT, msg_W, msgT, upd_W, updT, x, xb, eidx, deg, E, n4, M);
    scan_offsets<<<dim3(1), blk, 0, stream>>>(deg, offs, cursor, M);
    // CSR fill || in-GEMM (independent of each other)
    fill_ingemm<<<dim3(fillU + gemmBlocks), blk, 0, stream>>>(
        eidx, cursor, srcs, E, xb, WinT, b_in, B0, M, Mtiles);

    // layer 0
    gemm_f16<<<dim3(gemmBlocks), blk, 0, stream>>>(B0, 8, nullptr, 0,
        msgT, 8, 0, msg_b, B1, M, Mtiles, 0, 1,
        nullptr, nullptr, nullptr);                              // msg -> B1 row-major
    aggregate_f16<<<aggrGrid, blk, 0, stream>>>(B1, offs, srcs, B2, M,
        (float*)d_out, M);                                       // + re-zero d_out
    gemm_f16<<<dim3(gemmBlocks), blk, 0, stream>>>(B0, 8, B2, 8,
        updT, 16, 8, upd_b, B1, M, Mtiles, 1, 1,
        nullptr, nullptr, nullptr);                              // upd -> B1 packed
    // layer 1
    gemm_f16<<<dim3(gemmBlocks), blk, 0, stream>>>(B1, 8, nullptr, 0,
        msgT + 512 * 512, 8, 0, msg_b + 512, B0, M, Mtiles, 0, 1,
        nullptr, nullptr, nullptr);                              // msg -> B0 row-major
    aggregate_f16<<<aggrGrid, blk, 0, stream>>>(B0, offs, srcs, B2, M,
        nullptr, 0);
    // upd l1 with FUSED final dot: no C write, atomicAdd into d_out
    gemm_f16<<<dim3(gemmBlocks), blk, 0, stream>>>(B1, 8, B2, 8,
        updT + 512 * 1024, 16, 8, upd_b + 512, nullptr, M, Mtiles, 1, 1,
        W_out, b_out, (float*)d_out);
}